// Round 11
// baseline (349.087 us; speedup 1.0000x reference)
//
#include <hip/hip_runtime.h>
#include <stdint.h>

// RNN scan: h_t = tanh(h_{t-1} @ Whh + b_hh + x_t * Wxh + b_xh), out = h_T @ Wout + b_out
// B=16384 rows, T=1024 steps, H=32 hidden.
//
// Round 12 = round-9 structure (206us rocprof; r10's 2-wave j-split REVERTED --
// barrier phase-locked the sibling waves: occupancy doubled, dur regressed 13%)
// + Newton-rcp tanh: replace the 16-cyc v_rcp with 5 FMAs + 1 bfi on a BOUNDED
// domain. e = 2^(-|a|) in (0,1], h' = (1+e)/2 in (0.5,1]; cubic seed for 1/h'
// (eps ~3e-3) + one Newton (eps ~9e-6 rel, 50x below the f16 h-quant noise);
// tanh(|s|) = 1/h' - 1 folds the -1 into the Newton FMA; sign via one v_bfi
// (copysign). exp2 arg is always <= 0: no overflow path. Trans ops/step: 16 -> 8.
// Busy model (validated r8/r9): 343 -> ~300 cyc/step.
//
// Kept verbatim (harness-verified): j-quad [0,2,1,3] column permutation,
// v_permlane32_swap_b32 j->k redistribution (bit-exact), single-f16 RTN h state
// (mix-as-converter pack), x in registers, zero LDS, 1024 blocks x 64 thr.
//
// MFMA 16x16x32 f16 layouts (m89-verified):
//   A: lane l: m = l&15, k = 8*(l>>4)+e    B: lane l: n = l&15, k = 8*(l>>4)+e
//   D: lane l: n = l&15, m = 4*(l>>4)+reg

typedef _Float16 half8  __attribute__((ext_vector_type(8)));
typedef float    f32x4  __attribute__((ext_vector_type(4)));
typedef uint32_t u32x4  __attribute__((ext_vector_type(4)));

constexpr int Tlen   = 1024;
constexpr int NTILES = 16384 / 16;            // 1024 blocks, 16 rows each

constexpr float KSC = 2.8853900817779268f;    // +2*log2(e)

// tanh via bounded-domain Newton reciprocal (no v_rcp):
//   e = 2^(-|a|) in (0,1];  h = (1+e)/2 in (0.5,1];  rr = 1/h in [1,2)
//   tanh(|s|) = (1-e)/(1+e) = rr - 1;  tanh(s) = copysign(rr-1, a)
// cubic Chebyshev seed p(h) ~ 1/h on [0.5,1] (abs err ~3e-3), 1 Newton -> ~9e-6.
__device__ __forceinline__ float tanh_newton(float a) {
    float e  = __builtin_amdgcn_exp2f(-__builtin_fabsf(a));   // VOP3 -|src| mods
    float h  = __builtin_fmaf(0.5f, e, 0.5f);
    float r0 = __builtin_fmaf(
                   __builtin_fmaf(
                       __builtin_fmaf(-3.657037f, h, 10.892685f),
                       h, -11.937478f),
                   h, 5.699738f);
    float u  = __builtin_fmaf(-h, r0, 2.0f);                  // 2 - h*r0
    float m  = __builtin_fmaf(r0, u, -1.0f);                  // r0*u - 1 = rr - 1
    return __builtin_copysignf(m, a);                          // v_bfi
}

// RTN f32->f16 pair pack using v_fma_mix as converter (t*1+0, lo/hi halves).
__device__ __forceinline__ uint32_t cvt_pack_pair(float tLo, float tHi,
                                                  float one, float zero) {
    uint32_t w;
    asm("v_fma_mixlo_f16 %0, %1, %2, %3" : "=v"(w) : "v"(tLo), "v"(one), "v"(zero));
    asm("v_fma_mixhi_f16 %0, %1, %2, %3" : "+v"(w) : "v"(tHi), "v"(one), "v"(zero));
    return w;
}

// One permlane32_swap: X' = {X.lo32, Y.lo32}, Y' = {X.hi32, Y.hi32}.
// (round-6/7/8/9 harness-verified: matches the cndmask routing table bit-exactly)
__device__ __forceinline__ void pl32swap(uint32_t& xv, uint32_t& yv) {
    asm("v_permlane32_swap_b32 %0, %1" : "+v"(xv), "+v"(yv));
}

__global__ __launch_bounds__(64, 1)
void rnn_scan_mfma(const float* __restrict__ x,    // [B,T]
                   const float* __restrict__ Wxh,  // [1,H]
                   const float* __restrict__ b_xh, // [H]
                   const float* __restrict__ Whh,  // [H,H] row-major (i,j)
                   const float* __restrict__ b_hh, // [H]
                   const float* __restrict__ Wout, // [H,1]
                   const float* __restrict__ b_out,// [1]
                   float* __restrict__ out)        // [B,1]
{
    const int  lane = threadIdx.x;  // 0..63 (single-wave block)
    const int  r16  = lane & 15;
    const int  G    = lane >> 4;    // 0..3
    const int  tile = blockIdx.x;

    // ---- A fragments: RTN(K*Whh^T) with j-quad permutation [0,2,1,3] ------------
    const int mq   = r16 >> 2;
    const int mqp  = ((mq & 1) << 1) | (mq >> 1);
    const int col0 = 4 * mqp + (r16 & 3);          // colp(m), m = l&15

    half8 W1a, W1b;                                // [half: j<16 / j>=16]
    #pragma unroll
    for (int e = 0; e < 8; ++e) {
        int i = 8 * G + e;                         // k = i (Whh row)
        W1a[e] = (_Float16)(KSC * Whh[i * 32 + col0]);
        W1b[e] = (_Float16)(KSC * Whh[i * 32 + col0 + 16]);
    }

    // D reg q of MFMA0 -> j = 4*gp + q ; MFMA1 -> +16  (gp = permuted G)
    const int gp = ((G & 1) << 1) | (G >> 1);
    const int jb = 4 * gp;
    float wx0[4], wx1[4], bb0[4], bb1[4], wo0[4], wo1[4];
    #pragma unroll
    for (int q = 0; q < 4; ++q) {
        int j0 = jb + q, j1 = j0 + 16;
        wx0[q] = KSC * Wxh[j0];
        bb0[q] = KSC * (b_hh[j0] + b_xh[j0]);
        wo0[q] = Wout[j0];
        wx1[q] = KSC * Wxh[j1];
        bb1[q] = KSC * (b_hh[j1] + b_xh[j1]);
        wo1[q] = Wout[j1];
    }
    const float bout = b_out[0];
    const float one = 1.0f, zero = 0.0f;           // mix-converter constants

    const float* xrow = x + (size_t)(tile * 16 + r16) * Tlen;

    // h state: single-term f16 B-fragment words (k-pairs), h0 = 0
    uint32_t b1w0 = 0, b1w1 = 0, b1w2 = 0, b1w3 = 0;
    float t0 = 0.f, t1 = 0.f, t2 = 0.f, t3 = 0.f;
    float t4 = 0.f, t5 = 0.f, t6 = 0.f, t7 = 0.f;

    auto step = [&](float xv) {
        f32x4 c0, c1v;
        #pragma unroll
        for (int q = 0; q < 4; ++q) {
            c0[q]  = __builtin_fmaf(xv, wx0[q], bb0[q]);
            c1v[q] = __builtin_fmaf(xv, wx1[q], bb1[q]);
        }

        u32x4 u1 = {b1w0, b1w1, b1w2, b1w3};
        half8 hb1 = __builtin_bit_cast(half8, u1);

        // main matmul: D = K*(h@Whh + x*Wxh + b) in two j-halves
        f32x4 a0 = __builtin_amdgcn_mfma_f32_16x16x32_f16(W1a, hb1, c0,  0, 0, 0);
        f32x4 a1 = __builtin_amdgcn_mfma_f32_16x16x32_f16(W1b, hb1, c1v, 0, 0, 0);

        t0 = tanh_newton(a0[0]);
        t1 = tanh_newton(a0[1]);
        t2 = tanh_newton(a0[2]);
        t3 = tanh_newton(a0[3]);
        t4 = tanh_newton(a1[0]);
        t5 = tanh_newton(a1[1]);
        t6 = tanh_newton(a1[2]);
        t7 = tanh_newton(a1[3]);

        // RTN f16 pack + j->k redistribution (2 permlane swaps)
        uint32_t wA0 = cvt_pack_pair(t0, t1, one, zero);
        uint32_t wA1 = cvt_pack_pair(t2, t3, one, zero);
        uint32_t wB0 = cvt_pack_pair(t4, t5, one, zero);
        uint32_t wB1 = cvt_pack_pair(t6, t7, one, zero);
        pl32swap(wA0, wB0);  b1w0 = wA0;  b1w2 = wB0;
        pl32swap(wA1, wB1);  b1w1 = wA1;  b1w3 = wB1;
    };

    // x in registers: 8 steps per iteration (2 x float4), prefetched one iter ahead.
    float4 xa = *(const float4*)&xrow[0];
    float4 xb = *(const float4*)&xrow[4];
    #pragma unroll 1
    for (int t8 = 0; t8 < Tlen / 8 - 1; ++t8) {
        float4 na = *(const float4*)&xrow[8 * t8 +  8];
        float4 nb = *(const float4*)&xrow[8 * t8 + 12];
        step(xa.x); step(xa.y); step(xa.z); step(xa.w);
        step(xb.x); step(xb.y); step(xb.z); step(xb.w);
        xa = na; xb = nb;
    }
    step(xa.x); step(xa.y); step(xa.z); step(xa.w);   // last 8 steps (no prefetch)
    step(xb.x); step(xb.y); step(xb.z); step(xb.w);

    // out[row] = sum_j h_T[row][j]*Wout[j] + b_out; reduce over G-orbit {r,r+16,r+32,r+48}
    float v = t0 * wo0[0] + t1 * wo0[1] + t2 * wo0[2] + t3 * wo0[3]
            + t4 * wo1[0] + t5 * wo1[1] + t6 * wo1[2] + t7 * wo1[3];
    v += __shfl_xor(v, 16, 64);
    v += __shfl_xor(v, 32, 64);
    if (G == 0) out[tile * 16 + r16] = v + bout;
}

extern "C" void kernel_launch(void* const* d_in, const int* in_sizes, int n_in,
                              void* d_out, int out_size, void* d_ws, size_t ws_size,
                              hipStream_t stream) {
    const float* x     = (const float*)d_in[0];
    const float* Wxh   = (const float*)d_in[1];
    const float* b_xh  = (const float*)d_in[2];
    const float* Whh   = (const float*)d_in[3];
    const float* b_hh  = (const float*)d_in[4];
    const float* Wout  = (const float*)d_in[5];
    const float* b_out = (const float*)d_in[6];
    float* outp = (float*)d_out;

    rnn_scan_mfma<<<NTILES, 64, 0, stream>>>(x, Wxh, b_xh, Whh, b_hh, Wout,
                                             b_out, outp);
}